// Round 2
// baseline (2356.343 us; speedup 1.0000x reference)
//
#include <hip/hip_runtime.h>
#include <math.h>

#define N_ROWS 8192
#define K_DIM  7168
#define N_EXP  256
#define BM 32
#define BK 16
#define NTILES (K_DIM / BK)   // 448

// One block = 32 rows x all 256 experts. fp64 accumulation, fp64 routing.
__global__ __launch_bounds__(256) void moe_router_kernel(
    const float* __restrict__ x,      // [N_ROWS, K_DIM]
    const float* __restrict__ W,      // [K_DIM, N_EXP]
    const float* __restrict__ bias,   // [N_EXP]
    float* __restrict__ out_idx,      // [N_ROWS, 8] as float
    float* __restrict__ out_w,        // [N_ROWS, 8]
    float* __restrict__ out_s)        // [N_ROWS, N_EXP]
{
    __shared__ union U {
        struct {
            double ws_d[BK][N_EXP];     // 32 KB
            double xs_d[BK][BM + 4];    // 4.6 KB, row stride 36*8=288B (16B aligned)
        } st;
        double sc[BM][N_EXP + 1];       // 65.8 KB (row stride 257 doubles: 2-way banks)
    } u;
    __shared__ float bias_s[N_EXP];

    const int tid  = threadIdx.x;
    const int rb   = blockIdx.x * BM;
    const int trow = tid >> 5;          // 0..7  -> rows trow*4..+3
    const int tcol = tid & 31;          // 0..31 -> cols tcol*4..+3 and 128+tcol*4..+3

    bias_s[tid] = bias[tid];

    double acc[4][8] = {};

    // staging decomposition
    const int x_row = tid >> 2;         // 0..63 (use tid<128 -> 0..31)
    const int x_kp  = (tid & 3) * 4;    // 0,4,8,12

    float4 wreg[4];
    float4 xreg = {0.f, 0.f, 0.f, 0.f};

    auto load_tile = [&](int k0) {
        #pragma unroll
        for (int q = 0; q < 4; ++q) {
            int idx = tid + q * 256;    // 0..1023
            int kr  = idx >> 6;         // 0..15
            int c4  = (idx & 63) << 2;  // 0..252
            wreg[q] = *(const float4*)(W + (size_t)(k0 + kr) * N_EXP + c4);
        }
        if (tid < 128)
            xreg = *(const float4*)(x + (size_t)(rb + x_row) * K_DIM + k0 + x_kp);
    };
    auto store_tile = [&]() {
        #pragma unroll
        for (int q = 0; q < 4; ++q) {
            int idx = tid + q * 256;
            int kr  = idx >> 6;
            int c4  = (idx & 63) << 2;
            u.st.ws_d[kr][c4 + 0] = (double)wreg[q].x;
            u.st.ws_d[kr][c4 + 1] = (double)wreg[q].y;
            u.st.ws_d[kr][c4 + 2] = (double)wreg[q].z;
            u.st.ws_d[kr][c4 + 3] = (double)wreg[q].w;
        }
        if (tid < 128) {
            u.st.xs_d[x_kp + 0][x_row] = (double)xreg.x;
            u.st.xs_d[x_kp + 1][x_row] = (double)xreg.y;
            u.st.xs_d[x_kp + 2][x_row] = (double)xreg.z;
            u.st.xs_d[x_kp + 3][x_row] = (double)xreg.w;
        }
    };

    load_tile(0);
    for (int t = 0; t < NTILES; ++t) {
        __syncthreads();                 // previous tile's LDS reads done
        store_tile();
        __syncthreads();
        if (t + 1 < NTILES) load_tile((t + 1) * BK);  // hide latency under compute

        #pragma unroll
        for (int kk = 0; kk < BK; ++kk) {
            double a[4], b[8];
            #pragma unroll
            for (int i = 0; i < 4; ++i) a[i] = u.st.xs_d[kk][trow * 4 + i];
            #pragma unroll
            for (int j = 0; j < 4; ++j) {
                b[j]     = u.st.ws_d[kk][tcol * 4 + j];
                b[4 + j] = u.st.ws_d[kk][128 + tcol * 4 + j];
            }
            #pragma unroll
            for (int i = 0; i < 4; ++i)
                #pragma unroll
                for (int j = 0; j < 8; ++j)
                    acc[i][j] = fma(a[i], b[j], acc[i][j]);
        }
    }

    __syncthreads();   // done reading staging LDS; union becomes score buffer

    // sigmoid (fp64) -> LDS scores + global fp32 scores
    #pragma unroll
    for (int i = 0; i < 4; ++i) {
        int r = trow * 4 + i;
        #pragma unroll
        for (int j = 0; j < 8; ++j) {
            int c = (j < 4) ? (tcol * 4 + j) : (128 + tcol * 4 + (j - 4));
            double s = 1.0 / (1.0 + exp(-acc[i][j]));
            u.sc[r][c] = s;
            out_s[(size_t)(rb + r) * N_EXP + c] = (float)s;
        }
    }
    __syncthreads();

    // routing: one thread per row, fp64 decisions
    if (tid < BM) {
        const int row = rb + tid;
        const double* s = u.sc[tid];

        // group scores: sum of top-2 (score + bias) per group of 32
        double gs[8];
        #pragma unroll
        for (int g = 0; g < 8; ++g) {
            double m1 = -INFINITY, m2 = -INFINITY;
            for (int e = 0; e < 32; ++e) {
                double v = s[g * 32 + e] + (double)bias_s[g * 32 + e];
                if (v > m1) { m2 = m1; m1 = v; }
                else if (v > m2) { m2 = v; }
            }
            gs[g] = m1 + m2;
        }

        // top-4 groups, ties -> lower index
        unsigned gmask = 0;
        for (int t = 0; t < 4; ++t) {
            double best = -INFINITY; int bg = 0;
            for (int g = 0; g < 8; ++g)
                if (!((gmask >> g) & 1) && gs[g] > best) { best = gs[g]; bg = g; }
            gmask |= 1u << bg;
        }

        // top-8 experts among selected groups: stable insertion (ascending index,
        // strict >) == lax.top_k tie semantics
        double tv[8]; int ti[8];
        for (int j = 0; j < 8; ++j) { tv[j] = -INFINITY; ti[j] = -1; }
        for (int g = 0; g < 8; ++g) {
            if (!((gmask >> g) & 1)) continue;
            for (int e = 0; e < 32; ++e) {
                int idx = g * 32 + e;
                double v = s[idx] + (double)bias_s[idx];
                if (v > tv[7]) {
                    int j = 7;
                    while (j > 0 && v > tv[j - 1]) {
                        tv[j] = tv[j - 1]; ti[j] = ti[j - 1]; --j;
                    }
                    tv[j] = v; ti[j] = idx;
                }
            }
        }

        // weights from pure sigmoid scores, normalized, x2.5
        double wv[8]; double wsum = 0.0;
        for (int k = 0; k < 8; ++k) { wv[k] = s[ti[k]]; wsum += wv[k]; }
        double inv = 2.5 / (wsum + 1e-20);
        #pragma unroll
        for (int k = 0; k < 8; ++k) {
            out_idx[(size_t)row * 8 + k] = (float)ti[k];
            out_w[(size_t)row * 8 + k]   = (float)(wv[k] * inv);
        }
    }
}

extern "C" void kernel_launch(void* const* d_in, const int* in_sizes, int n_in,
                              void* d_out, int out_size, void* d_ws, size_t ws_size,
                              hipStream_t stream) {
    const float* x    = (const float*)d_in[0];
    const float* W    = (const float*)d_in[1];
    const float* bias = (const float*)d_in[2];

    float* out     = (float*)d_out;
    float* out_idx = out;                  // [8192*8]
    float* out_w   = out + N_ROWS * 8;     // [8192*8]
    float* out_s   = out + N_ROWS * 16;    // [8192*256]

    moe_router_kernel<<<N_ROWS / BM, 256, 0, stream>>>(x, W, bias, out_idx, out_w, out_s);
}

// Round 3
// 1492.587 us; speedup vs baseline: 1.5787x; 1.5787x over previous
//
#include <hip/hip_runtime.h>
#include <math.h>

#define N_ROWS 8192
#define K_DIM  7168
#define N_EXP  256

// Flag windows (score units). fp32-GEMM logit error std ~6e-6 -> score err ~1.5e-6.
// Windows are ~26 sigma: essentially zero chance an ambiguous decision goes unflagged.
#define THETA_S 4e-5
#define THETA_G 1.6e-4

// ================= Phase 1: fp32 GEMM, logits -> out_s =================
#define P1_BM 32
#define P1_BN 128
#define P1_BK 32
#define P1_NT (K_DIM / P1_BK)   // 224

__global__ __launch_bounds__(256) void p1_gemm_logits(
    const float* __restrict__ x, const float* __restrict__ W,
    float* __restrict__ logits)
{
    __shared__ float xs[P1_BK][36];      // [k][row], stride 144B (16B aligned)
    __shared__ float ws[P1_BK][P1_BN];   // [k][col]

    const int tid  = threadIdx.x;
    const int trow = tid >> 5;           // 0..7 -> rows trow*4..+3
    const int tcol = tid & 31;           // 0..31 -> cols tcol*4..+3
    const int rb   = blockIdx.y * P1_BM;
    const int cb   = blockIdx.x * P1_BN;

    float acc[4][4] = {};

    const int xr = tid >> 3;             // 0..31
    const int xk = (tid & 7) * 4;        // 0..28

    float4 wreg[4];
    float4 xreg;

    auto load_tile = [&](int k0) {
        #pragma unroll
        for (int q = 0; q < 4; ++q) {
            int idx = tid + q * 256, kr = idx >> 5, c4 = (idx & 31) * 4;
            wreg[q] = *(const float4*)(W + (size_t)(k0 + kr) * N_EXP + cb + c4);
        }
        xreg = *(const float4*)(x + (size_t)(rb + xr) * K_DIM + k0 + xk);
    };
    auto store_tile = [&]() {
        #pragma unroll
        for (int q = 0; q < 4; ++q) {
            int idx = tid + q * 256, kr = idx >> 5, c4 = (idx & 31) * 4;
            *(float4*)&ws[kr][c4] = wreg[q];
        }
        xs[xk + 0][xr] = xreg.x; xs[xk + 1][xr] = xreg.y;
        xs[xk + 2][xr] = xreg.z; xs[xk + 3][xr] = xreg.w;
    };

    load_tile(0);
    for (int t = 0; t < P1_NT; ++t) {
        __syncthreads();
        store_tile();
        __syncthreads();
        if (t + 1 < P1_NT) load_tile((t + 1) * P1_BK);

        #pragma unroll
        for (int kk = 0; kk < P1_BK; ++kk) {
            float4 a = *(const float4*)&xs[kk][trow * 4];   // broadcast (2 addrs/wave)
            float4 b = *(const float4*)&ws[kk][tcol * 4];   // contiguous 512B
            float av[4] = {a.x, a.y, a.z, a.w};
            float bv[4] = {b.x, b.y, b.z, b.w};
            #pragma unroll
            for (int i = 0; i < 4; ++i)
                #pragma unroll
                for (int j = 0; j < 4; ++j)
                    acc[i][j] = fmaf(av[i], bv[j], acc[i][j]);
        }
    }

    #pragma unroll
    for (int i = 0; i < 4; ++i) {
        float4 o = {acc[i][0], acc[i][1], acc[i][2], acc[i][3]};
        *(float4*)(logits + (size_t)(rb + trow * 4 + i) * N_EXP + cb + tcol * 4) = o;
    }
}

// ================= Phase 2: route + flag (1 thread / row) =================
__global__ void p2_route(
    float* __restrict__ sc,            // in: logits, out: sigmoid scores (fp32)
    const float* __restrict__ bias,
    float* __restrict__ out_idx, float* __restrict__ out_w,
    int* __restrict__ flag_cnt, int* __restrict__ flag_list)
{
    int row = blockIdx.x * blockDim.x + threadIdx.x;
    if (row >= N_ROWS) return;
    float* s = sc + (size_t)row * N_EXP;

    // pass A: sigmoid in place, per-group top-2 sum of (score + bias)
    double gs[8];
    #pragma unroll
    for (int g = 0; g < 8; ++g) {
        double m1 = -1e300, m2 = -1e300;
        for (int e4 = 0; e4 < 8; ++e4) {
            int base = g * 32 + e4 * 4;
            float4 l4 = *(float4*)&s[base];
            float4 s4;
            s4.x = 1.0f / (1.0f + expf(-l4.x));
            s4.y = 1.0f / (1.0f + expf(-l4.y));
            s4.z = 1.0f / (1.0f + expf(-l4.z));
            s4.w = 1.0f / (1.0f + expf(-l4.w));
            *(float4*)&s[base] = s4;
            float svv[4] = {s4.x, s4.y, s4.z, s4.w};
            #pragma unroll
            for (int c = 0; c < 4; ++c) {
                double v = (double)svv[c] + (double)bias[base + c];
                if (v > m1) { m2 = m1; m1 = v; }
                else if (v > m2) { m2 = v; }
            }
        }
        gs[g] = m1 + m2;
    }

    // top-4 groups (strict >, lower index wins) + 4th/5th gap
    unsigned gmask = 0;
    double v4 = 0.0, v5 = 0.0;
    for (int t = 0; t < 5; ++t) {
        double best = -1e300; int bg = 0;
        for (int g = 0; g < 8; ++g)
            if (!((gmask >> g) & 1) && gs[g] > best) { best = gs[g]; bg = g; }
        if (t < 4) { gmask |= 1u << bg; if (t == 3) v4 = best; }
        else v5 = best;
    }
    bool flag = (v4 - v5) < THETA_G;

    // pass B: stable top-9 of (score+bias) among selected groups
    double tv[9]; int ti[9];
    #pragma unroll
    for (int j = 0; j < 9; ++j) { tv[j] = -1e300; ti[j] = -1; }
    for (int g = 0; g < 8; ++g) {
        if (!((gmask >> g) & 1)) continue;
        for (int e = 0; e < 32; ++e) {
            int idx = g * 32 + e;
            double v = (double)s[idx] + (double)bias[idx];
            if (v > tv[8]) {
                int j = 8;
                while (j > 0 && v > tv[j - 1]) { tv[j] = tv[j-1]; ti[j] = ti[j-1]; --j; }
                tv[j] = v; ti[j] = idx;
            }
        }
    }
    #pragma unroll
    for (int k = 0; k < 8; ++k)
        if (tv[k] - tv[k + 1] < THETA_S) flag = true;

    if (flag) {
        int p = atomicAdd(flag_cnt, 1);
        if (p < N_ROWS) flag_list[p] = row;
    } else {
        double wsum = 0.0; float wv[8];
        #pragma unroll
        for (int k = 0; k < 8; ++k) { wv[k] = s[ti[k]]; wsum += (double)wv[k]; }
        double inv = 2.5 / (wsum + 1e-20);
        #pragma unroll
        for (int k = 0; k < 8; ++k) {
            out_idx[(size_t)row * 8 + k] = (float)ti[k];
            out_w[(size_t)row * 8 + k]   = (float)((double)wv[k] * inv);
        }
    }
}

// ================= Phase 3: fp64 fixup for flagged rows =================
#define P3_RPB 4
#define P3_KC  1024

__global__ __launch_bounds__(256) void p3_fixup(
    const float* __restrict__ x, const float* __restrict__ W,
    const float* __restrict__ bias,
    float* __restrict__ out_idx, float* __restrict__ out_w, float* __restrict__ out_s,
    const int* __restrict__ flag_cnt, const int* __restrict__ flag_list)
{
    __shared__ float  xls[P3_RPB][P3_KC];     // 16 KB
    __shared__ double scl[P3_RPB][N_EXP + 1]; // 8.2 KB
    __shared__ int    rid[P3_RPB];
    __shared__ float  bias_s[N_EXP];

    const int count = *flag_cnt;
    const int base  = blockIdx.x * P3_RPB;
    if (base >= count) return;
    const int nr  = min(P3_RPB, count - base);
    const int tid = threadIdx.x;

    bias_s[tid] = bias[tid];
    if (tid < P3_RPB) rid[tid] = flag_list[base + min(tid, nr - 1)];
    __syncthreads();

    const int e = tid;   // this thread's expert column
    double acc[P3_RPB] = {0.0, 0.0, 0.0, 0.0};

    for (int kc = 0; kc < K_DIM; kc += P3_KC) {
        // stage 4 rows x 1024 k of x
        #pragma unroll
        for (int q = 0; q < 4; ++q) {
            int idx = tid + q * 256;      // 0..1023
            int r = idx >> 8, f4 = (idx & 255) * 4;
            *(float4*)&xls[r][f4] = *(const float4*)(x + (size_t)rid[r] * K_DIM + kc + f4);
        }
        __syncthreads();

        for (int kk = 0; kk < P3_KC; kk += 2) {
            double w0 = (double)W[(size_t)(kc + kk)     * N_EXP + e];
            double w1 = (double)W[(size_t)(kc + kk + 1) * N_EXP + e];
            #pragma unroll
            for (int r = 0; r < P3_RPB; ++r) {
                float2 xv = *(const float2*)&xls[r][kk];  // broadcast
                acc[r] = fma((double)xv.x, w0, acc[r]);
                acc[r] = fma((double)xv.y, w1, acc[r]);
            }
        }
        __syncthreads();
    }

    #pragma unroll
    for (int r = 0; r < P3_RPB; ++r)
        scl[r][e] = 1.0 / (1.0 + exp(-acc[r]));
    __syncthreads();

    // write fp32 scores for the valid rows
    for (int r = 0; r < nr; ++r)
        out_s[(size_t)rid[r] * N_EXP + e] = (float)scl[r][e];

    // routing, fp64, one thread per valid row (identical to the passing r2 logic)
    if (tid < nr) {
        const int row = rid[tid];
        const double* s = scl[tid];

        double gsv[8];
        #pragma unroll
        for (int g = 0; g < 8; ++g) {
            double m1 = -1e300, m2 = -1e300;
            for (int ee = 0; ee < 32; ++ee) {
                double v = s[g * 32 + ee] + (double)bias_s[g * 32 + ee];
                if (v > m1) { m2 = m1; m1 = v; }
                else if (v > m2) { m2 = v; }
            }
            gsv[g] = m1 + m2;
        }
        unsigned gmask = 0;
        for (int t = 0; t < 4; ++t) {
            double best = -1e300; int bg = 0;
            for (int g = 0; g < 8; ++g)
                if (!((gmask >> g) & 1) && gsv[g] > best) { best = gsv[g]; bg = g; }
            gmask |= 1u << bg;
        }
        double tv[8]; int ti[8];
        #pragma unroll
        for (int j = 0; j < 8; ++j) { tv[j] = -1e300; ti[j] = -1; }
        for (int g = 0; g < 8; ++g) {
            if (!((gmask >> g) & 1)) continue;
            for (int ee = 0; ee < 32; ++ee) {
                int idx = g * 32 + ee;
                double v = s[idx] + (double)bias_s[idx];
                if (v > tv[7]) {
                    int j = 7;
                    while (j > 0 && v > tv[j - 1]) { tv[j] = tv[j-1]; ti[j] = ti[j-1]; --j; }
                    tv[j] = v; ti[j] = idx;
                }
            }
        }
        double wv[8]; double wsum = 0.0;
        #pragma unroll
        for (int k = 0; k < 8; ++k) { wv[k] = s[ti[k]]; wsum += wv[k]; }
        double inv = 2.5 / (wsum + 1e-20);
        #pragma unroll
        for (int k = 0; k < 8; ++k) {
            out_idx[(size_t)row * 8 + k] = (float)ti[k];
            out_w[(size_t)row * 8 + k]   = (float)(wv[k] * inv);
        }
    }
}

extern "C" void kernel_launch(void* const* d_in, const int* in_sizes, int n_in,
                              void* d_out, int out_size, void* d_ws, size_t ws_size,
                              hipStream_t stream) {
    const float* x    = (const float*)d_in[0];
    const float* W    = (const float*)d_in[1];
    const float* bias = (const float*)d_in[2];

    float* out     = (float*)d_out;
    float* out_idx = out;                  // [8192*8]
    float* out_w   = out + N_ROWS * 8;     // [8192*8]
    float* out_s   = out + N_ROWS * 16;    // [8192*256]

    int* flag_cnt  = (int*)d_ws;
    int* flag_list = (int*)d_ws + 4;       // 16B offset

    hipMemsetAsync(flag_cnt, 0, sizeof(int), stream);

    dim3 g1(N_EXP / P1_BN, N_ROWS / P1_BM);   // (2, 256)
    p1_gemm_logits<<<g1, 256, 0, stream>>>(x, W, out_s);

    p2_route<<<N_ROWS / 256, 256, 0, stream>>>(out_s, bias, out_idx, out_w,
                                               flag_cnt, flag_list);

    p3_fixup<<<(N_ROWS + P3_RPB - 1) / P3_RPB, 256, 0, stream>>>(
        x, W, bias, out_idx, out_w, out_s, flag_cnt, flag_list);
}

// Round 4
// 1124.116 us; speedup vs baseline: 2.0962x; 1.3278x over previous
//
#include <hip/hip_runtime.h>
#include <math.h>

#define N_ROWS 8192
#define K_DIM  7168
#define N_EXP  256

// Flag windows (score units). fp32-GEMM logit error std ~6e-6 -> score err ~1.5e-6.
#define THETA_S 4e-5
#define THETA_G 1.6e-4

typedef unsigned int u32;

__device__ __forceinline__ void gload_lds16(const float* g, float* l) {
    __builtin_amdgcn_global_load_lds(
        (const __attribute__((address_space(1))) u32*)(g),
        (__attribute__((address_space(3))) u32*)(l), 16, 0, 0);
}
__device__ __forceinline__ void gload_lds4(const float* g, float* l) {
    __builtin_amdgcn_global_load_lds(
        (const __attribute__((address_space(1))) u32*)(g),
        (__attribute__((address_space(3))) u32*)(l), 4, 0, 0);
}

// ================= Phase 1: fp32 GEMM, logits -> out_s =================
// BM=32, BN=128, BK=32; 256 threads (4 waves); grid (2,256)=512 blocks.
// global_load_lds staging, double-buffered LDS, one barrier per tile.
#define P1_BM 32
#define P1_BN 128
#define P1_BK 32
#define P1_NT (K_DIM / P1_BK)   // 224

__global__ __launch_bounds__(256, 2) void p1_gemm_logits(
    const float* __restrict__ x, const float* __restrict__ W,
    float* __restrict__ logits)
{
    __shared__ float xs[2][P1_BK * P1_BM];    // linear [kk*32+row], 2x4KB
    __shared__ float ws[2][P1_BK * P1_BN];    // linear [kk*128+col], 2x16KB

    const int tid  = threadIdx.x;
    const int w    = tid >> 6;          // wave 0..3
    const int lane = tid & 63;
    const int trow = tid >> 5;          // 0..7
    const int tcol = tid & 31;          // 0..31
    const int rb   = blockIdx.y * P1_BM;
    const int cb   = blockIdx.x * P1_BN;

    float acc[4][4] = {};

    // staging source pointers (advance by BK each tile)
    const float* gx[4];
    const float* gw[4];
    #pragma unroll
    for (int q = 0; q < 4; ++q) {
        int L = (w * 4 + q) * 64 + lane;            // x element: kk=L>>5, row=L&31
        gx[q] = x + (size_t)(rb + (L & 31)) * K_DIM + (L >> 5);
        int F = ((w * 4 + q) * 64 + lane) * 4;      // W element: kk=F>>7, col=F&127
        gw[q] = W + (size_t)(F >> 7) * N_EXP + cb + (F & 127);
    }

    auto stage = [&](int buf) {
        #pragma unroll
        for (int q = 0; q < 4; ++q)
            gload_lds16(gw[q], &ws[buf][(w * 4 + q) * 256]);
        #pragma unroll
        for (int q = 0; q < 4; ++q)
            gload_lds4(gx[q], &xs[buf][(w * 4 + q) * 64]);
        #pragma unroll
        for (int q = 0; q < 4; ++q) {
            gw[q] += (size_t)P1_BK * N_EXP;
            gx[q] += P1_BK;
        }
    };

    auto compute = [&](int buf) {
        #pragma unroll
        for (int kk = 0; kk < P1_BK; ++kk) {
            float4 av = *(const float4*)&xs[buf][kk * 32 + trow * 4];
            float4 bv = *(const float4*)&ws[buf][kk * 128 + tcol * 4];
            float aa[4] = {av.x, av.y, av.z, av.w};
            float bb[4] = {bv.x, bv.y, bv.z, bv.w};
            #pragma unroll
            for (int i = 0; i < 4; ++i)
                #pragma unroll
                for (int j = 0; j < 4; ++j)
                    acc[i][j] = fmaf(aa[i], bb[j], acc[i][j]);
        }
    };

    stage(0);
    asm volatile("s_waitcnt vmcnt(0)" ::: "memory");
    __syncthreads();

    int cur = 0;
    for (int t = 0; t < P1_NT; ++t) {
        if (t + 1 < P1_NT) stage(cur ^ 1);
        compute(cur);
        asm volatile("s_waitcnt vmcnt(0)" ::: "memory");
        __syncthreads();
        cur ^= 1;
    }

    #pragma unroll
    for (int i = 0; i < 4; ++i) {
        float4 o = {acc[i][0], acc[i][1], acc[i][2], acc[i][3]};
        *(float4*)(logits + (size_t)(rb + trow * 4 + i) * N_EXP + cb + tcol * 4) = o;
    }
}

// ================= Phase 2: route + flag (1 wave / row, register-only) =====
__global__ __launch_bounds__(256) void p2_route(
    float* __restrict__ sc,            // in: logits, out: sigmoid scores
    const float* __restrict__ bias,
    float* __restrict__ out_idx, float* __restrict__ out_w,
    int* __restrict__ flag_cnt, int* __restrict__ flag_list)
{
    const int lane = threadIdx.x & 63;
    const int row  = blockIdx.x * 4 + (threadIdx.x >> 6);
    float* s = sc + (size_t)row * N_EXP;
    const int ib = lane * 4;            // this lane's 4 experts

    float4 l4 = *(const float4*)&s[ib];
    float4 s4;
    s4.x = 1.0f / (1.0f + expf(-l4.x));
    s4.y = 1.0f / (1.0f + expf(-l4.y));
    s4.z = 1.0f / (1.0f + expf(-l4.z));
    s4.w = 1.0f / (1.0f + expf(-l4.w));
    *(float4*)&s[ib] = s4;              // final scores output (in-place)

    float4 b4 = *(const float4*)&bias[ib];
    float v0 = s4.x + b4.x, v1 = s4.y + b4.y, v2 = s4.z + b4.z, v3 = s4.w + b4.w;

    // ---- group top-2 (8 lanes per group of 32 experts) ----
    float a = fmaxf(v0, v1), b = fminf(v0, v1);
    float c = fmaxf(v2, v3), d = fminf(v2, v3);
    float m1 = fmaxf(a, c);
    float m2 = fmaxf(fminf(a, c), fmaxf(b, d));
    #pragma unroll
    for (int off = 1; off <= 4; off <<= 1) {
        float o1 = __shfl_xor(m1, off);
        float o2 = __shfl_xor(m2, off);
        float hi = fmaxf(m1, o1), lo = fminf(m1, o1);
        m2 = fmaxf(lo, fmaxf(m2, o2));
        m1 = hi;
    }
    float gsum = m1 + m2;
    float gv[8];
    #pragma unroll
    for (int g = 0; g < 8; ++g) gv[g] = __shfl(gsum, g * 8);

    // ---- top-4 groups (strict >, lower index wins) + 4th/5th gap ----
    unsigned gmask = 0;
    float g4 = 0.f, g5 = 0.f;
    #pragma unroll
    for (int t = 0; t < 5; ++t) {
        float best = -INFINITY; int bg = 0;
        #pragma unroll
        for (int g = 0; g < 8; ++g)
            if (!((gmask >> g) & 1) && gv[g] > best) { best = gv[g]; bg = g; }
        if (t < 4) { gmask |= 1u << bg; if (t == 3) g4 = best; }
        else g5 = best;
    }
    bool flag = (g4 - g5) < (float)THETA_G;

    // ---- top-9 experts among selected groups: 9 extraction rounds ----
    bool sel = (gmask >> (lane >> 3)) & 1;
    float c0 = sel ? v0 : -INFINITY;
    float c1 = sel ? v1 : -INFINITY;
    float c2 = sel ? v2 : -INFINITY;
    float c3 = sel ? v3 : -INFINITY;

    float tvv[9]; int tii[9];
    #pragma unroll
    for (int r = 0; r < 9; ++r) {
        float lv = c0; int li = ib;
        if (c1 > lv) { lv = c1; li = ib + 1; }
        if (c2 > lv) { lv = c2; li = ib + 2; }
        if (c3 > lv) { lv = c3; li = ib + 3; }
        #pragma unroll
        for (int off = 1; off < 64; off <<= 1) {
            float ov = __shfl_xor(lv, off);
            int   oi = __shfl_xor(li, off);
            if (ov > lv || (ov == lv && oi < li)) { lv = ov; li = oi; }
        }
        tvv[r] = lv; tii[r] = li;     // identical on all lanes
        if      (li == ib)     c0 = -INFINITY;
        else if (li == ib + 1) c1 = -INFINITY;
        else if (li == ib + 2) c2 = -INFINITY;
        else if (li == ib + 3) c3 = -INFINITY;
    }
    #pragma unroll
    for (int k = 0; k < 8; ++k)
        if (tvv[k] - tvv[k + 1] < (float)THETA_S) flag = true;

    if (flag) {
        if (lane == 0) {
            int p = atomicAdd(flag_cnt, 1);
            flag_list[p] = row;
        }
        return;
    }

    // ---- weights: gather sigmoid scores via shuffle, fp64 normalize ----
    float wv[8]; double wsum = 0.0;
    #pragma unroll
    for (int k = 0; k < 8; ++k) {
        int t = tii[k];                       // wave-uniform
        int j = t & 3;
        float svv = (j == 0) ? s4.x : (j == 1) ? s4.y : (j == 2) ? s4.z : s4.w;
        float wk = __shfl(svv, t >> 2);
        wv[k] = wk; wsum += (double)wk;
    }
    double inv = 2.5 / (wsum + 1e-20);
    if (lane == 0) {
        #pragma unroll
        for (int k = 0; k < 8; ++k) {
            out_idx[(size_t)row * 8 + k] = (float)tii[k];
            out_w[(size_t)row * 8 + k]   = (float)((double)wv[k] * inv);
        }
    }
}

// ================= Phase 3: fp64 fixup for flagged rows =================
#define P3_RPB 4
#define P3_KC  1024

__global__ __launch_bounds__(256) void p3_fixup(
    const float* __restrict__ x, const float* __restrict__ W,
    const float* __restrict__ bias,
    float* __restrict__ out_idx, float* __restrict__ out_w, float* __restrict__ out_s,
    const int* __restrict__ flag_cnt, const int* __restrict__ flag_list)
{
    __shared__ float  xls[P3_RPB][P3_KC];
    __shared__ double scl[P3_RPB][N_EXP + 1];
    __shared__ int    rid[P3_RPB];
    __shared__ float  bias_s[N_EXP];

    const int count = *flag_cnt;
    const int base  = blockIdx.x * P3_RPB;
    if (base >= count) return;
    const int nr  = min(P3_RPB, count - base);
    const int tid = threadIdx.x;

    bias_s[tid] = bias[tid];
    if (tid < P3_RPB) rid[tid] = flag_list[base + min(tid, nr - 1)];
    __syncthreads();

    const int e = tid;
    double acc[P3_RPB] = {0.0, 0.0, 0.0, 0.0};

    for (int kc = 0; kc < K_DIM; kc += P3_KC) {
        #pragma unroll
        for (int q = 0; q < 4; ++q) {
            int idx = tid + q * 256;
            int r = idx >> 8, f4 = (idx & 255) * 4;
            *(float4*)&xls[r][f4] = *(const float4*)(x + (size_t)rid[r] * K_DIM + kc + f4);
        }
        __syncthreads();

        for (int kk = 0; kk < P3_KC; kk += 2) {
            double w0 = (double)W[(size_t)(kc + kk)     * N_EXP + e];
            double w1 = (double)W[(size_t)(kc + kk + 1) * N_EXP + e];
            #pragma unroll
            for (int r = 0; r < P3_RPB; ++r) {
                float2 xv = *(const float2*)&xls[r][kk];
                acc[r] = fma((double)xv.x, w0, acc[r]);
                acc[r] = fma((double)xv.y, w1, acc[r]);
            }
        }
        __syncthreads();
    }

    #pragma unroll
    for (int r = 0; r < P3_RPB; ++r)
        scl[r][e] = 1.0 / (1.0 + exp(-acc[r]));
    __syncthreads();

    for (int r = 0; r < nr; ++r)
        out_s[(size_t)rid[r] * N_EXP + e] = (float)scl[r][e];

    if (tid < nr) {
        const int row = rid[tid];
        const double* s = scl[tid];

        double gsv[8];
        #pragma unroll
        for (int g = 0; g < 8; ++g) {
            double m1 = -1e300, m2 = -1e300;
            for (int ee = 0; ee < 32; ++ee) {
                double v = s[g * 32 + ee] + (double)bias_s[g * 32 + ee];
                if (v > m1) { m2 = m1; m1 = v; }
                else if (v > m2) { m2 = v; }
            }
            gsv[g] = m1 + m2;
        }
        unsigned gmask = 0;
        for (int t = 0; t < 4; ++t) {
            double best = -1e300; int bg = 0;
            for (int g = 0; g < 8; ++g)
                if (!((gmask >> g) & 1) && gsv[g] > best) { best = gsv[g]; bg = g; }
            gmask |= 1u << bg;
        }
        double tv[8]; int ti[8];
        #pragma unroll
        for (int j = 0; j < 8; ++j) { tv[j] = -1e300; ti[j] = -1; }
        for (int g = 0; g < 8; ++g) {
            if (!((gmask >> g) & 1)) continue;
            for (int ee = 0; ee < 32; ++ee) {
                int idx = g * 32 + ee;
                double v = s[idx] + (double)bias_s[idx];
                if (v > tv[7]) {
                    int j = 7;
                    while (j > 0 && v > tv[j - 1]) { tv[j] = tv[j-1]; ti[j] = ti[j-1]; --j; }
                    tv[j] = v; ti[j] = idx;
                }
            }
        }
        double wv[8]; double wsum = 0.0;
        #pragma unroll
        for (int k = 0; k < 8; ++k) { wv[k] = s[ti[k]]; wsum += wv[k]; }
        double inv = 2.5 / (wsum + 1e-20);
        #pragma unroll
        for (int k = 0; k < 8; ++k) {
            out_idx[(size_t)row * 8 + k] = (float)ti[k];
            out_w[(size_t)row * 8 + k]   = (float)(wv[k] * inv);
        }
    }
}

extern "C" void kernel_launch(void* const* d_in, const int* in_sizes, int n_in,
                              void* d_out, int out_size, void* d_ws, size_t ws_size,
                              hipStream_t stream) {
    const float* x    = (const float*)d_in[0];
    const float* W    = (const float*)d_in[1];
    const float* bias = (const float*)d_in[2];

    float* out     = (float*)d_out;
    float* out_idx = out;                  // [8192*8]
    float* out_w   = out + N_ROWS * 8;     // [8192*8]
    float* out_s   = out + N_ROWS * 16;    // [8192*256]

    int* flag_cnt  = (int*)d_ws;
    int* flag_list = (int*)d_ws + 4;

    hipMemsetAsync(flag_cnt, 0, sizeof(int), stream);

    dim3 g1(N_EXP / P1_BN, N_ROWS / P1_BM);   // (2, 256)
    p1_gemm_logits<<<g1, 256, 0, stream>>>(x, W, out_s);

    p2_route<<<N_ROWS / 4, 256, 0, stream>>>(out_s, bias, out_idx, out_w,
                                             flag_cnt, flag_list);

    p3_fixup<<<(N_ROWS + P3_RPB - 1) / P3_RPB, 256, 0, stream>>>(
        x, W, bias, out_idx, out_w, out_s, flag_cnt, flag_list);
}

// Round 5
// 765.174 us; speedup vs baseline: 3.0795x; 1.4691x over previous
//
#include <hip/hip_runtime.h>
#include <math.h>

#define N_ROWS 8192
#define K_DIM  7168
#define N_EXP  256

// Flag windows (score units). fp32 logit err sigma ~5e-6; at top scores the
// sigmoid slope is ~0.02 -> score err sigma ~1e-7..1.25e-6 (worst slope 0.25
// only at s=0.5, never for top candidates). These are >=16 sigma worst-case.
#define THETA_S 6e-6f
#define THETA_G 1.2e-5f

typedef unsigned int u32;

__device__ __forceinline__ void gload_lds16(const float* g, float* l) {
    __builtin_amdgcn_global_load_lds(
        (const __attribute__((address_space(1))) u32*)(g),
        (__attribute__((address_space(3))) u32*)(l), 16, 0, 0);
}
__device__ __forceinline__ void gload_lds4(const float* g, float* l) {
    __builtin_amdgcn_global_load_lds(
        (const __attribute__((address_space(1))) u32*)(g),
        (__attribute__((address_space(3))) u32*)(l), 4, 0, 0);
}

// ================= Phase 1: fp32 GEMM, logits -> out_s =================
// BM=32, BN=64, BK=32; 256 threads (4 waves); grid (4,256)=1024 blocks (4/CU).
#define P1_BM 32
#define P1_BN 64
#define P1_BK 32
#define P1_NT (K_DIM / P1_BK)   // 224

__global__ __launch_bounds__(256, 4) void p1_gemm_logits(
    const float* __restrict__ x, const float* __restrict__ W,
    float* __restrict__ logits)
{
    __shared__ float xs[2][P1_BK * P1_BM];    // linear [kk*32+row], 2x4KB
    __shared__ float ws[2][P1_BK * P1_BN];    // linear [kk*64+col], 2x8KB

    const int tid  = threadIdx.x;
    const int w    = tid >> 6;          // wave 0..3
    const int lane = tid & 63;
    const int trow = tid >> 5;          // 0..7 -> rows trow*4..+3
    const int tcol = tid & 31;          // 0..31 -> cols tcol*2..+1
    const int rb   = blockIdx.y * P1_BM;
    const int cb   = blockIdx.x * P1_BN;

    float acc[4][2] = {};

    const float* gx[4];
    const float* gw[2];
    #pragma unroll
    for (int q = 0; q < 4; ++q) {
        int L = (w * 4 + q) * 64 + lane;            // xs idx: kk=L>>5, row=L&31
        gx[q] = x + (size_t)(rb + (L & 31)) * K_DIM + (L >> 5);
    }
    #pragma unroll
    for (int q = 0; q < 2; ++q) {
        int F = ((w * 2 + q) * 64 + lane) * 4;      // ws idx: kk=F>>6, col=F&63
        gw[q] = W + (size_t)(F >> 6) * N_EXP + cb + (F & 63);
    }

    auto stage = [&](int buf) {
        #pragma unroll
        for (int q = 0; q < 2; ++q)
            gload_lds16(gw[q], &ws[buf][(w * 2 + q) * 256]);
        #pragma unroll
        for (int q = 0; q < 4; ++q)
            gload_lds4(gx[q], &xs[buf][(w * 4 + q) * 64]);
        #pragma unroll
        for (int q = 0; q < 2; ++q) gw[q] += (size_t)P1_BK * N_EXP;
        #pragma unroll
        for (int q = 0; q < 4; ++q) gx[q] += P1_BK;
    };

    auto compute = [&](int buf) {
        #pragma unroll
        for (int kk = 0; kk < P1_BK; ++kk) {
            float4 av = *(const float4*)&xs[buf][kk * 32 + trow * 4];
            float2 bv = *(const float2*)&ws[buf][kk * 64 + tcol * 2];
            float aa[4] = {av.x, av.y, av.z, av.w};
            float bb[2] = {bv.x, bv.y};
            #pragma unroll
            for (int i = 0; i < 4; ++i)
                #pragma unroll
                for (int j = 0; j < 2; ++j)
                    acc[i][j] = fmaf(aa[i], bb[j], acc[i][j]);
        }
    };

    stage(0);
    asm volatile("s_waitcnt vmcnt(0)" ::: "memory");
    __syncthreads();

    int cur = 0;
    for (int t = 0; t < P1_NT; ++t) {
        if (t + 1 < P1_NT) stage(cur ^ 1);
        compute(cur);
        asm volatile("s_waitcnt vmcnt(0)" ::: "memory");
        __syncthreads();
        cur ^= 1;
    }

    #pragma unroll
    for (int i = 0; i < 4; ++i) {
        float2 o = {acc[i][0], acc[i][1]};
        *(float2*)(logits + (size_t)(rb + trow * 4 + i) * N_EXP + cb + tcol * 2) = o;
    }
}

// ================= Phase 2: route + flag (1 wave / row, register-only) =====
__global__ __launch_bounds__(256) void p2_route(
    float* __restrict__ sc,            // in: logits, out: sigmoid scores
    const float* __restrict__ bias,
    float* __restrict__ out_idx, float* __restrict__ out_w,
    int* __restrict__ flag_cnt, int* __restrict__ flag_list)
{
    const int lane = threadIdx.x & 63;
    const int row  = blockIdx.x * 4 + (threadIdx.x >> 6);
    float* s = sc + (size_t)row * N_EXP;
    const int ib = lane * 4;            // this lane's 4 experts

    float4 l4 = *(const float4*)&s[ib];
    float4 s4;
    s4.x = 1.0f / (1.0f + expf(-l4.x));
    s4.y = 1.0f / (1.0f + expf(-l4.y));
    s4.z = 1.0f / (1.0f + expf(-l4.z));
    s4.w = 1.0f / (1.0f + expf(-l4.w));
    *(float4*)&s[ib] = s4;              // final scores output (in-place)

    float4 b4 = *(const float4*)&bias[ib];
    float v0 = s4.x + b4.x, v1 = s4.y + b4.y, v2 = s4.z + b4.z, v3 = s4.w + b4.w;

    // ---- group top-2 (8 lanes per group of 32 experts) ----
    float a = fmaxf(v0, v1), b = fminf(v0, v1);
    float c = fmaxf(v2, v3), d = fminf(v2, v3);
    float m1 = fmaxf(a, c);
    float m2 = fmaxf(fminf(a, c), fmaxf(b, d));
    #pragma unroll
    for (int off = 1; off <= 4; off <<= 1) {
        float o1 = __shfl_xor(m1, off);
        float o2 = __shfl_xor(m2, off);
        float hi = fmaxf(m1, o1), lo = fminf(m1, o1);
        m2 = fmaxf(lo, fmaxf(m2, o2));
        m1 = hi;
    }
    float gsum = m1 + m2;
    float gv[8];
    #pragma unroll
    for (int g = 0; g < 8; ++g) gv[g] = __shfl(gsum, g * 8);

    // ---- top-4 groups (strict >, lower index wins) + 4th/5th gap ----
    unsigned gmask = 0;
    float g4 = 0.f, g5 = 0.f;
    #pragma unroll
    for (int t = 0; t < 5; ++t) {
        float best = -INFINITY; int bg = 0;
        #pragma unroll
        for (int g = 0; g < 8; ++g)
            if (!((gmask >> g) & 1) && gv[g] > best) { best = gv[g]; bg = g; }
        if (t < 4) { gmask |= 1u << bg; if (t == 3) g4 = best; }
        else g5 = best;
    }
    bool flag = (g4 - g5) < THETA_G;

    // ---- top-9 experts among selected groups: 9 extraction rounds ----
    bool sel = (gmask >> (lane >> 3)) & 1;
    float c0 = sel ? v0 : -INFINITY;
    float c1 = sel ? v1 : -INFINITY;
    float c2 = sel ? v2 : -INFINITY;
    float c3 = sel ? v3 : -INFINITY;

    float tvv[9]; int tii[9];
    #pragma unroll
    for (int r = 0; r < 9; ++r) {
        float lv = c0; int li = ib;
        if (c1 > lv) { lv = c1; li = ib + 1; }
        if (c2 > lv) { lv = c2; li = ib + 2; }
        if (c3 > lv) { lv = c3; li = ib + 3; }
        #pragma unroll
        for (int off = 1; off < 64; off <<= 1) {
            float ov = __shfl_xor(lv, off);
            int   oi = __shfl_xor(li, off);
            if (ov > lv || (ov == lv && oi < li)) { lv = ov; li = oi; }
        }
        tvv[r] = lv; tii[r] = li;     // identical on all lanes
        if      (li == ib)     c0 = -INFINITY;
        else if (li == ib + 1) c1 = -INFINITY;
        else if (li == ib + 2) c2 = -INFINITY;
        else if (li == ib + 3) c3 = -INFINITY;
    }
    #pragma unroll
    for (int k = 0; k < 8; ++k)
        if (tvv[k] - tvv[k + 1] < THETA_S) flag = true;

    if (flag) {
        if (lane == 0) {
            int p = atomicAdd(flag_cnt, 1);
            if (p < N_ROWS) flag_list[p] = row;
        }
        return;
    }

    // ---- weights: gather sigmoid scores via shuffle, fp64 normalize ----
    float wv[8]; double wsum = 0.0;
    #pragma unroll
    for (int k = 0; k < 8; ++k) {
        int t = tii[k];                       // wave-uniform
        int j = t & 3;
        float svv = (j == 0) ? s4.x : (j == 1) ? s4.y : (j == 2) ? s4.z : s4.w;
        float wk = __shfl(svv, t >> 2);
        wv[k] = wk; wsum += (double)wk;
    }
    double inv = 2.5 / (wsum + 1e-20);
    if (lane == 0) {
        #pragma unroll
        for (int k = 0; k < 8; ++k) {
            out_idx[(size_t)row * 8 + k] = (float)tii[k];
            out_w[(size_t)row * 8 + k]   = (float)((double)wv[k] * inv);
        }
    }
}

// ================= Phase 3: fp64 fixup, 1 row per block =================
// 1024 threads = 256 experts x 4 K-slices. Wave 0 routes (fp64, register-only).
#define P3_KS 4
#define P3_KC (K_DIM / P3_KS)   // 1792

__global__ __launch_bounds__(1024) void p3_fixup(
    const float* __restrict__ x, const float* __restrict__ W,
    const float* __restrict__ bias,
    float* __restrict__ out_idx, float* __restrict__ out_w,
    const int* __restrict__ flag_cnt, const int* __restrict__ flag_list)
{
    int count = *flag_cnt;
    if (count > N_ROWS) count = N_ROWS;
    if ((int)blockIdx.x >= count) return;
    const int row = flag_list[blockIdx.x];

    __shared__ double pr[P3_KS][N_EXP];   // 8KB
    __shared__ double scl[N_EXP];         // 2KB

    const int tid = threadIdx.x;
    const int e   = tid & 255;
    const int ks  = tid >> 8;             // 0..3

    const float* xp = x + (size_t)row * K_DIM + ks * P3_KC;
    const float* wp = W + (size_t)(ks * P3_KC) * N_EXP + e;

    double acc = 0.0;
    #pragma unroll 4
    for (int j = 0; j < P3_KC; ++j)
        acc = fma((double)xp[j], (double)wp[(size_t)j * N_EXP], acc);

    pr[ks][e] = acc;
    __syncthreads();
    if (tid < N_EXP) {
        double l = pr[0][tid] + pr[1][tid] + pr[2][tid] + pr[3][tid];
        scl[tid] = 1.0 / (1.0 + exp(-l));
    }
    __syncthreads();
    if (tid >= 64) return;                 // wave 0 routes

    const int lane = tid;
    const int ib = lane * 4;
    double s0 = scl[ib], s1 = scl[ib + 1], s2 = scl[ib + 2], s3 = scl[ib + 3];
    double v0 = s0 + (double)bias[ib];
    double v1 = s1 + (double)bias[ib + 1];
    double v2 = s2 + (double)bias[ib + 2];
    double v3 = s3 + (double)bias[ib + 3];

    // group top-2
    double a = fmax(v0, v1), b = fmin(v0, v1);
    double c = fmax(v2, v3), d = fmin(v2, v3);
    double m1 = fmax(a, c);
    double m2 = fmax(fmin(a, c), fmax(b, d));
    #pragma unroll
    for (int off = 1; off <= 4; off <<= 1) {
        double o1 = __shfl_xor(m1, off);
        double o2 = __shfl_xor(m2, off);
        double hi = fmax(m1, o1), lo = fmin(m1, o1);
        m2 = fmax(lo, fmax(m2, o2));
        m1 = hi;
    }
    double gsum = m1 + m2;
    double gvv[8];
    #pragma unroll
    for (int g = 0; g < 8; ++g) gvv[g] = __shfl(gsum, g * 8);

    unsigned gmask = 0;
    #pragma unroll
    for (int t = 0; t < 4; ++t) {
        double best = -1e300; int bg = 0;
        #pragma unroll
        for (int g = 0; g < 8; ++g)
            if (!((gmask >> g) & 1) && gvv[g] > best) { best = gvv[g]; bg = g; }
        gmask |= 1u << bg;
    }

    bool sel = (gmask >> (lane >> 3)) & 1;
    double c0 = sel ? v0 : -1e300;
    double c1 = sel ? v1 : -1e300;
    double c2 = sel ? v2 : -1e300;
    double c3 = sel ? v3 : -1e300;

    int tii[8];
    #pragma unroll
    for (int r = 0; r < 8; ++r) {
        double lv = c0; int li = ib;
        if (c1 > lv) { lv = c1; li = ib + 1; }
        if (c2 > lv) { lv = c2; li = ib + 2; }
        if (c3 > lv) { lv = c3; li = ib + 3; }
        #pragma unroll
        for (int off = 1; off < 64; off <<= 1) {
            double ov = __shfl_xor(lv, off);
            int    oi = __shfl_xor(li, off);
            if (ov > lv || (ov == lv && oi < li)) { lv = ov; li = oi; }
        }
        tii[r] = li;
        if      (li == ib)     c0 = -1e300;
        else if (li == ib + 1) c1 = -1e300;
        else if (li == ib + 2) c2 = -1e300;
        else if (li == ib + 3) c3 = -1e300;
    }

    double wv[8]; double wsum = 0.0;
    #pragma unroll
    for (int k = 0; k < 8; ++k) {
        int t = tii[k];                       // wave-uniform
        int j = t & 3;
        double svv = (j == 0) ? s0 : (j == 1) ? s1 : (j == 2) ? s2 : s3;
        double wk = __shfl(svv, t >> 2);
        wv[k] = wk; wsum += wk;
    }
    double inv = 2.5 / (wsum + 1e-20);
    if (lane == 0) {
        #pragma unroll
        for (int k = 0; k < 8; ++k) {
            out_idx[(size_t)row * 8 + k] = (float)tii[k];
            out_w[(size_t)row * 8 + k]   = (float)(wv[k] * inv);
        }
    }
}

extern "C" void kernel_launch(void* const* d_in, const int* in_sizes, int n_in,
                              void* d_out, int out_size, void* d_ws, size_t ws_size,
                              hipStream_t stream) {
    const float* x    = (const float*)d_in[0];
    const float* W    = (const float*)d_in[1];
    const float* bias = (const float*)d_in[2];

    float* out     = (float*)d_out;
    float* out_idx = out;                  // [8192*8]
    float* out_w   = out + N_ROWS * 8;     // [8192*8]
    float* out_s   = out + N_ROWS * 16;    // [8192*256]

    int* flag_cnt  = (int*)d_ws;
    int* flag_list = (int*)d_ws + 4;

    hipMemsetAsync(flag_cnt, 0, sizeof(int), stream);

    dim3 g1(N_EXP / P1_BN, N_ROWS / P1_BM);   // (4, 256) = 1024 blocks
    p1_gemm_logits<<<g1, 256, 0, stream>>>(x, W, out_s);

    p2_route<<<N_ROWS / 4, 256, 0, stream>>>(out_s, bias, out_idx, out_w,
                                             flag_cnt, flag_list);

    p3_fixup<<<N_ROWS, 1024, 0, stream>>>(x, W, bias, out_idx, out_w,
                                          flag_cnt, flag_list);
}

// Round 6
// 682.167 us; speedup vs baseline: 3.4542x; 1.1217x over previous
//
#include <hip/hip_runtime.h>
#include <math.h>

#define N_ROWS 8192
#define K_DIM  7168
#define N_EXP  256
#define NT     (K_DIM / 32)      // 224 K-chunks of 32

// Flag windows (score units), passed per path:
//  fp32 path:  logit err sigma ~8.6e-6 -> 6e-6 / 1.2e-5  (proven r5)
//  mfma path:  logit err sigma ~2.2e-5 -> 6e-5 / 1.2e-4  (>=12 sigma)
#define FLAG_CAP 2048

typedef unsigned int u32;
typedef short short8 __attribute__((ext_vector_type(8)));
typedef float f32x4  __attribute__((ext_vector_type(4)));

__device__ __forceinline__ void gload_lds16(const void* g, void* l) {
    __builtin_amdgcn_global_load_lds(
        (const __attribute__((address_space(1))) u32*)(g),
        (__attribute__((address_space(3))) u32*)(l), 16, 0, 0);
}
__device__ __forceinline__ void gload_lds4(const void* g, void* l) {
    __builtin_amdgcn_global_load_lds(
        (const __attribute__((address_space(1))) u32*)(g),
        (__attribute__((address_space(3))) u32*)(l), 4, 0, 0);
}

__device__ __forceinline__ void split_bf16(float v, unsigned short& hi, unsigned short& lo) {
    u32 ub = __float_as_uint(v);
    u32 hb = (ub + 0x7FFFu + ((ub >> 16) & 1u)) >> 16;
    float hv = __uint_as_float(hb << 16);
    float r  = v - hv;
    u32 rb2 = __float_as_uint(r);
    u32 lb2 = (rb2 + 0x7FFFu + ((rb2 >> 16) & 1u)) >> 16;
    hi = (unsigned short)hb;
    lo = (unsigned short)lb2;
}

// ============ p0: W -> split bf16 image in ws (MFMA-ready tiled layout) =====
// Image per (chunk c, half h): 8192 u16 = [ hi[4 kg][128 n][8 j] | lo[...] ]
__global__ __launch_bounds__(128) void p0_wprep(
    const float* __restrict__ W, unsigned short* __restrict__ wimg)
{
    const int bid = blockIdx.x;            // c*8 + h*4 + kg
    const int c  = bid >> 3;
    const int h  = (bid >> 2) & 1;
    const int kg = bid & 3;
    const int n  = threadIdx.x;            // 0..127

    short8 h8, l8;
    #pragma unroll
    for (int j = 0; j < 8; ++j) {
        float v = W[(size_t)(c * 32 + kg * 8 + j) * N_EXP + h * 128 + n];
        unsigned short hi, lo;
        split_bf16(v, hi, lo);
        h8[j] = (short)hi; l8[j] = (short)lo;
    }
    size_t base = (size_t)(c * 2 + h) * 8192;
    *(short8*)(wimg + base + (size_t)(kg * 128 + n) * 8)        = h8;
    *(short8*)(wimg + base + 4096 + (size_t)(kg * 128 + n) * 8) = l8;
}

// ============ p1 (MFMA): logits via 3-term bf16 split =======================
// 512 blocks x 128 thr (2 waves). BM=32, BN=128. Wave tile 32x64 (2m x 4n frags
// of 16x16x32). LDS dbuf, counted vmcnt, raw barrier.
__global__ __launch_bounds__(128) void p1_mfma(
    const float* __restrict__ x, const unsigned short* __restrict__ wimg,
    float* __restrict__ logits)
{
    // buffer: [ B hi 4096 | B lo 4096 | A hi 1024 | A lo 1024 ] u16 = 20KB
    __shared__ unsigned short lds[2][10240];

    const int tid  = threadIdx.x;
    const int lane = tid & 63;
    const int wid  = tid >> 6;             // 0..1
    // bijective chunked XCD swizzle (512 % 8 == 0): pairs (2r,2r+1) same XCD
    const int lb = (blockIdx.x & 7) * 64 + (blockIdx.x >> 3);
    const int rb = (lb >> 1) * 32;
    const int h  = lb & 1;
    const int cb = h * 128;

    const unsigned short* wsrc = wimg + (size_t)h * 8192;  // + c*16384 u16/chunk

    const int xrow = tid >> 2;             // 0..31
    const int xkg  = tid & 3;              // 0..3
    const float* xg = x + (size_t)(rb + xrow) * K_DIM + xkg * 8;

    f32x4 acc[2][4] = {};
    float4 xr[2][2];

    const int arow = lane & 15;
    const int akg  = lane >> 4;

    auto stageB = [&](int c, int buf) {
        const unsigned short* s = wsrc + (size_t)c * 16384;
        #pragma unroll
        for (int r = 0; r < 8; ++r)
            gload_lds16(s + (size_t)(r * 128 + tid) * 8, &lds[buf][(r * 128 + tid) * 8]);
    };
    auto loadx = [&](int c, int sl) {
        xr[sl][0] = *(const float4*)(xg + (size_t)c * 32);
        xr[sl][1] = *(const float4*)(xg + (size_t)c * 32 + 4);
    };
    auto writex = [&](int sl, int buf) {
        short8 h8, l8;
        float v[8] = {xr[sl][0].x, xr[sl][0].y, xr[sl][0].z, xr[sl][0].w,
                      xr[sl][1].x, xr[sl][1].y, xr[sl][1].z, xr[sl][1].w};
        #pragma unroll
        for (int j = 0; j < 8; ++j) {
            unsigned short hi, lo;
            split_bf16(v[j], hi, lo);
            h8[j] = (short)hi; l8[j] = (short)lo;
        }
        *(short8*)&lds[buf][8192 + xkg * 256 + xrow * 8] = h8;
        *(short8*)&lds[buf][9216 + xkg * 256 + xrow * 8] = l8;
    };
    auto compute = [&](int buf) {
        const unsigned short* L = lds[buf];
        short8 ah[2], al[2];
        #pragma unroll
        for (int m = 0; m < 2; ++m) {
            ah[m] = *(const short8*)&L[8192 + akg * 256 + (m * 16 + arow) * 8];
            al[m] = *(const short8*)&L[9216 + akg * 256 + (m * 16 + arow) * 8];
        }
        #pragma unroll
        for (int nf = 0; nf < 4; ++nf) {
            const int n = wid * 64 + nf * 16 + arow;
            short8 bh = *(const short8*)&L[akg * 1024 + n * 8];
            short8 bl = *(const short8*)&L[4096 + akg * 1024 + n * 8];
            #pragma unroll
            for (int m = 0; m < 2; ++m) {
                acc[m][nf] = __builtin_amdgcn_mfma_f32_16x16x32_bf16(ah[m], bh, acc[m][nf], 0, 0, 0);
                acc[m][nf] = __builtin_amdgcn_mfma_f32_16x16x32_bf16(ah[m], bl, acc[m][nf], 0, 0, 0);
                acc[m][nf] = __builtin_amdgcn_mfma_f32_16x16x32_bf16(al[m], bh, acc[m][nf], 0, 0, 0);
            }
        }
    };

    // prologue: B0 + x0,x1 in flight
    stageB(0, 0);
    loadx(0, 0);
    loadx(1, 1);
    asm volatile("s_waitcnt vmcnt(2)" ::: "memory");      // B0,x0 done (x1 flying)
    writex(0, 0);
    asm volatile("s_waitcnt lgkmcnt(0)" ::: "memory");
    __builtin_amdgcn_s_barrier();

    int p = 0, q = 1;
    for (int c = 0; c < NT; ++c) {
        if (c + 1 < NT) {
            stageB(c + 1, p ^ 1);                          // 8 VMEM
            loadx(min(c + 2, NT - 1), q ^ 1);              // 2 VMEM (dummy at tail)
            asm volatile("s_waitcnt vmcnt(10)" ::: "memory");  // x_{c+1} landed
            writex(q, p ^ 1);
        }
        compute(p);
        if (c + 1 < NT) {
            asm volatile("s_waitcnt vmcnt(2) lgkmcnt(0)" ::: "memory"); // B_{c+1} done
            __builtin_amdgcn_s_barrier();
        }
        p ^= 1; q ^= 1;
    }

    // epilogue: D frag row=(lane>>4)*4+r, col=lane&15  (m89-verified)
    #pragma unroll
    for (int m = 0; m < 2; ++m)
        #pragma unroll
        for (int nf = 0; nf < 4; ++nf) {
            const int col = cb + wid * 64 + nf * 16 + arow;
            #pragma unroll
            for (int r = 0; r < 4; ++r) {
                const int row = rb + m * 16 + akg * 4 + r;
                logits[(size_t)row * N_EXP + col] = acc[m][nf][r];
            }
        }
}

// ============ p1 fallback (fp32 VALU, proven r5) ============================
#define F1_BM 32
#define F1_BN 64
#define F1_BK 32
#define F1_NT (K_DIM / F1_BK)

__global__ __launch_bounds__(256, 4) void p1_fp32(
    const float* __restrict__ x, const float* __restrict__ W,
    float* __restrict__ logits)
{
    __shared__ float xs[2][F1_BK * F1_BM];
    __shared__ float ws[2][F1_BK * F1_BN];

    const int tid  = threadIdx.x;
    const int w    = tid >> 6;
    const int lane = tid & 63;
    const int trow = tid >> 5;
    const int tcol = tid & 31;
    const int rb   = blockIdx.y * F1_BM;
    const int cb   = blockIdx.x * F1_BN;

    float acc[4][2] = {};
    const float* gx[4];
    const float* gw[2];
    #pragma unroll
    for (int q = 0; q < 4; ++q) {
        int L = (w * 4 + q) * 64 + lane;
        gx[q] = x + (size_t)(rb + (L & 31)) * K_DIM + (L >> 5);
    }
    #pragma unroll
    for (int q = 0; q < 2; ++q) {
        int F = ((w * 2 + q) * 64 + lane) * 4;
        gw[q] = W + (size_t)(F >> 6) * N_EXP + cb + (F & 63);
    }
    auto stage = [&](int buf) {
        #pragma unroll
        for (int q = 0; q < 2; ++q) gload_lds16(gw[q], &ws[buf][(w * 2 + q) * 256]);
        #pragma unroll
        for (int q = 0; q < 4; ++q) gload_lds4(gx[q], &xs[buf][(w * 4 + q) * 64]);
        #pragma unroll
        for (int q = 0; q < 2; ++q) gw[q] += (size_t)F1_BK * N_EXP;
        #pragma unroll
        for (int q = 0; q < 4; ++q) gx[q] += F1_BK;
    };
    auto compute = [&](int buf) {
        #pragma unroll
        for (int kk = 0; kk < F1_BK; ++kk) {
            float4 av = *(const float4*)&xs[buf][kk * 32 + trow * 4];
            float2 bv = *(const float2*)&ws[buf][kk * 64 + tcol * 2];
            float aa[4] = {av.x, av.y, av.z, av.w};
            float bb[2] = {bv.x, bv.y};
            #pragma unroll
            for (int i = 0; i < 4; ++i)
                #pragma unroll
                for (int j = 0; j < 2; ++j)
                    acc[i][j] = fmaf(aa[i], bb[j], acc[i][j]);
        }
    };
    stage(0);
    asm volatile("s_waitcnt vmcnt(0)" ::: "memory");
    __syncthreads();
    int cur = 0;
    for (int t = 0; t < F1_NT; ++t) {
        if (t + 1 < F1_NT) stage(cur ^ 1);
        compute(cur);
        asm volatile("s_waitcnt vmcnt(0)" ::: "memory");
        __syncthreads();
        cur ^= 1;
    }
    #pragma unroll
    for (int i = 0; i < 4; ++i) {
        float2 o = {acc[i][0], acc[i][1]};
        *(float2*)(logits + (size_t)(rb + trow * 4 + i) * N_EXP + cb + tcol * 2) = o;
    }
}

// ============ p2: route + flag (1 wave / row), always writes ================
__global__ __launch_bounds__(256) void p2_route(
    float* __restrict__ sc, const float* __restrict__ bias,
    float* __restrict__ out_idx, float* __restrict__ out_w,
    int* __restrict__ flag_cnt, int* __restrict__ flag_list,
    float thS, float thG)
{
    const int lane = threadIdx.x & 63;
    const int row  = blockIdx.x * 4 + (threadIdx.x >> 6);
    float* s = sc + (size_t)row * N_EXP;
    const int ib = lane * 4;

    float4 l4 = *(const float4*)&s[ib];
    float4 s4;
    s4.x = 1.0f / (1.0f + expf(-l4.x));
    s4.y = 1.0f / (1.0f + expf(-l4.y));
    s4.z = 1.0f / (1.0f + expf(-l4.z));
    s4.w = 1.0f / (1.0f + expf(-l4.w));
    *(float4*)&s[ib] = s4;

    float4 b4 = *(const float4*)&bias[ib];
    float v0 = s4.x + b4.x, v1 = s4.y + b4.y, v2 = s4.z + b4.z, v3 = s4.w + b4.w;

    float a = fmaxf(v0, v1), b = fminf(v0, v1);
    float c = fmaxf(v2, v3), d = fminf(v2, v3);
    float m1 = fmaxf(a, c);
    float m2 = fmaxf(fminf(a, c), fmaxf(b, d));
    #pragma unroll
    for (int off = 1; off <= 4; off <<= 1) {
        float o1 = __shfl_xor(m1, off);
        float o2 = __shfl_xor(m2, off);
        float hi = fmaxf(m1, o1), lo = fminf(m1, o1);
        m2 = fmaxf(lo, fmaxf(m2, o2));
        m1 = hi;
    }
    float gsum = m1 + m2;
    float gv[8];
    #pragma unroll
    for (int g = 0; g < 8; ++g) gv[g] = __shfl(gsum, g * 8);

    unsigned gmask = 0;
    float g4 = 0.f, g5 = 0.f;
    #pragma unroll
    for (int t = 0; t < 5; ++t) {
        float best = -INFINITY; int bg = 0;
        #pragma unroll
        for (int g = 0; g < 8; ++g)
            if (!((gmask >> g) & 1) && gv[g] > best) { best = gv[g]; bg = g; }
        if (t < 4) { gmask |= 1u << bg; if (t == 3) g4 = best; }
        else g5 = best;
    }
    bool flag = (g4 - g5) < thG;

    bool sel = (gmask >> (lane >> 3)) & 1;
    float c0 = sel ? v0 : -INFINITY;
    float c1 = sel ? v1 : -INFINITY;
    float c2 = sel ? v2 : -INFINITY;
    float c3 = sel ? v3 : -INFINITY;

    float tvv[9]; int tii[9];
    #pragma unroll
    for (int r = 0; r < 9; ++r) {
        float lv = c0; int li = ib;
        if (c1 > lv) { lv = c1; li = ib + 1; }
        if (c2 > lv) { lv = c2; li = ib + 2; }
        if (c3 > lv) { lv = c3; li = ib + 3; }
        #pragma unroll
        for (int off = 1; off < 64; off <<= 1) {
            float ov = __shfl_xor(lv, off);
            int   oi = __shfl_xor(li, off);
            if (ov > lv || (ov == lv && oi < li)) { lv = ov; li = oi; }
        }
        tvv[r] = lv; tii[r] = li;
        if      (li == ib)     c0 = -INFINITY;
        else if (li == ib + 1) c1 = -INFINITY;
        else if (li == ib + 2) c2 = -INFINITY;
        else if (li == ib + 3) c3 = -INFINITY;
    }
    #pragma unroll
    for (int k = 0; k < 8; ++k)
        if (tvv[k] - tvv[k + 1] < thS) flag = true;

    // always write (p3 overwrites flagged rows)
    float wv[8]; double wsum = 0.0;
    #pragma unroll
    for (int k = 0; k < 8; ++k) {
        int t = tii[k];
        int j = t & 3;
        float svv = (j == 0) ? s4.x : (j == 1) ? s4.y : (j == 2) ? s4.z : s4.w;
        float wk = __shfl(svv, t >> 2);
        wv[k] = wk; wsum += (double)wk;
    }
    double inv = 2.5 / (wsum + 1e-20);
    if (lane == 0) {
        #pragma unroll
        for (int k = 0; k < 8; ++k) {
            out_idx[(size_t)row * 8 + k] = (float)tii[k];
            out_w[(size_t)row * 8 + k]   = (float)((double)wv[k] * inv);
        }
        if (flag) {
            int pz = atomicAdd(flag_cnt, 1);
            if (pz < FLAG_CAP) flag_list[pz] = row;
        }
    }
}

// ============ p3: fp64 fixup, 1 row/block ===================================
#define P3_KS 4
#define P3_KC (K_DIM / P3_KS)

__global__ __launch_bounds__(1024) void p3_fixup(
    const float* __restrict__ x, const float* __restrict__ W,
    const float* __restrict__ bias,
    float* __restrict__ out_idx, float* __restrict__ out_w,
    const int* __restrict__ flag_cnt, const int* __restrict__ flag_list)
{
    int count = *flag_cnt;
    if (count > FLAG_CAP) count = FLAG_CAP;
    if ((int)blockIdx.x >= count) return;
    const int row = flag_list[blockIdx.x];

    __shared__ double pr[P3_KS][N_EXP];
    __shared__ double scl[N_EXP];

    const int tid = threadIdx.x;
    const int e   = tid & 255;
    const int ks  = tid >> 8;

    const float* xp = x + (size_t)row * K_DIM + ks * P3_KC;
    const float* wp = W + (size_t)(ks * P3_KC) * N_EXP + e;

    double acc = 0.0;
    #pragma unroll 4
    for (int j = 0; j < P3_KC; ++j)
        acc = fma((double)xp[j], (double)wp[(size_t)j * N_EXP], acc);

    pr[ks][e] = acc;
    __syncthreads();
    if (tid < N_EXP) {
        double l = pr[0][tid] + pr[1][tid] + pr[2][tid] + pr[3][tid];
        scl[tid] = 1.0 / (1.0 + exp(-l));
    }
    __syncthreads();
    if (tid >= 64) return;

    const int lane = tid;
    const int ib = lane * 4;
    double s0 = scl[ib], s1 = scl[ib + 1], s2 = scl[ib + 2], s3 = scl[ib + 3];
    double v0 = s0 + (double)bias[ib];
    double v1 = s1 + (double)bias[ib + 1];
    double v2 = s2 + (double)bias[ib + 2];
    double v3 = s3 + (double)bias[ib + 3];

    double a = fmax(v0, v1), b = fmin(v0, v1);
    double c = fmax(v2, v3), d = fmin(v2, v3);
    double m1 = fmax(a, c);
    double m2 = fmax(fmin(a, c), fmax(b, d));
    #pragma unroll
    for (int off = 1; off <= 4; off <<= 1) {
        double o1 = __shfl_xor(m1, off);
        double o2 = __shfl_xor(m2, off);
        double hi = fmax(m1, o1), lo = fmin(m1, o1);
        m2 = fmax(lo, fmax(m2, o2));
        m1 = hi;
    }
    double gsum = m1 + m2;
    double gvv[8];
    #pragma unroll
    for (int g = 0; g < 8; ++g) gvv[g] = __shfl(gsum, g * 8);

    unsigned gmask = 0;
    #pragma unroll
    for (int t = 0; t < 4; ++t) {
        double best = -1e300; int bg = 0;
        #pragma unroll
        for (int g = 0; g < 8; ++g)
            if (!((gmask >> g) & 1) && gvv[g] > best) { best = gvv[g]; bg = g; }
        gmask |= 1u << bg;
    }

    bool sel = (gmask >> (lane >> 3)) & 1;
    double c0 = sel ? v0 : -1e300;
    double c1 = sel ? v1 : -1e300;
    double c2 = sel ? v2 : -1e300;
    double c3 = sel ? v3 : -1e300;

    int tii[8];
    #pragma unroll
    for (int r = 0; r < 8; ++r) {
        double lv = c0; int li = ib;
        if (c1 > lv) { lv = c1; li = ib + 1; }
        if (c2 > lv) { lv = c2; li = ib + 2; }
        if (c3 > lv) { lv = c3; li = ib + 3; }
        #pragma unroll
        for (int off = 1; off < 64; off <<= 1) {
            double ov = __shfl_xor(lv, off);
            int    oi = __shfl_xor(li, off);
            if (ov > lv || (ov == lv && oi < li)) { lv = ov; li = oi; }
        }
        tii[r] = li;
        if      (li == ib)     c0 = -1e300;
        else if (li == ib + 1) c1 = -1e300;
        else if (li == ib + 2) c2 = -1e300;
        else if (li == ib + 3) c3 = -1e300;
    }

    double wv[8]; double wsum = 0.0;
    #pragma unroll
    for (int k = 0; k < 8; ++k) {
        int t = tii[k];
        int j = t & 3;
        double svv = (j == 0) ? s0 : (j == 1) ? s1 : (j == 2) ? s2 : s3;
        double wk = __shfl(svv, t >> 2);
        wv[k] = wk; wsum += wk;
    }
    double inv = 2.5 / (wsum + 1e-20);
    if (lane == 0) {
        #pragma unroll
        for (int k = 0; k < 8; ++k) {
            out_idx[(size_t)row * 8 + k] = (float)tii[k];
            out_w[(size_t)row * 8 + k]   = (float)(wv[k] * inv);
        }
    }
}

extern "C" void kernel_launch(void* const* d_in, const int* in_sizes, int n_in,
                              void* d_out, int out_size, void* d_ws, size_t ws_size,
                              hipStream_t stream) {
    const float* x    = (const float*)d_in[0];
    const float* W    = (const float*)d_in[1];
    const float* bias = (const float*)d_in[2];

    float* out     = (float*)d_out;
    float* out_idx = out;
    float* out_w   = out + N_ROWS * 8;
    float* out_s   = out + N_ROWS * 16;

    int* flag_cnt  = (int*)d_ws;
    int* flag_list = (int*)d_ws + 4;

    const size_t WIMG_OFF  = 65536;
    const size_t WIMG_SIZE = (size_t)NT * 32768;   // 7.0 MiB
    bool use_mfma = ws_size >= WIMG_OFF + WIMG_SIZE;

    hipMemsetAsync(flag_cnt, 0, sizeof(int), stream);

    if (use_mfma) {
        unsigned short* wimg = (unsigned short*)((char*)d_ws + WIMG_OFF);
        p0_wprep<<<NT * 8, 128, 0, stream>>>(W, wimg);
        p1_mfma<<<512, 128, 0, stream>>>(x, wimg, out_s);
        p2_route<<<N_ROWS / 4, 256, 0, stream>>>(out_s, bias, out_idx, out_w,
                                                 flag_cnt, flag_list, 6e-5f, 1.2e-4f);
    } else {
        dim3 g1(N_EXP / F1_BN, N_ROWS / F1_BM);
        p1_fp32<<<g1, 256, 0, stream>>>(x, W, out_s);
        p2_route<<<N_ROWS / 4, 256, 0, stream>>>(out_s, bias, out_idx, out_w,
                                                 flag_cnt, flag_list, 6e-6f, 1.2e-5f);
    }
    p3_fixup<<<FLAG_CAP, 1024, 0, stream>>>(x, W, bias, out_idx, out_w,
                                            flag_cnt, flag_list);
}